// Round 3
// baseline (356.884 us; speedup 1.0000x reference)
//
#include <hip/hip_runtime.h>
#include <hip/hip_bf16.h>
#include <stdint.h>

#define B_N 8192
#define D_K 512
#define TEMP_INV 10.0f   // 1/TEMPERATURE
#define HNW 1.5f         // 1 + HARD_NEG_WEIGHT

typedef short bf16x8 __attribute__((ext_vector_type(8)));
typedef float f32x4 __attribute__((ext_vector_type(4)));

// order-preserving float<->uint key for atomicMax on floats
__device__ __forceinline__ unsigned fkey(float f) {
  unsigned u = __float_as_uint(f);
  return (u & 0x80000000u) ? ~u : (u | 0x80000000u);
}
__device__ __forceinline__ float unkey(unsigned k) {
  unsigned u = (k & 0x80000000u) ? (k & 0x7FFFFFFFu) : ~k;
  return __uint_as_float(u);
}
__device__ __forceinline__ unsigned short f2bf(float f) {
  unsigned u = __float_as_uint(f);
  u += 0x7FFFu + ((u >> 16) & 1u);   // round-to-nearest-even
  return (unsigned short)(u >> 16);
}

__global__ void cvt_kernel(const float* __restrict__ in, unsigned short* __restrict__ out) {
  int i = (blockIdx.x * 256 + threadIdx.x) * 4;
  float4 f = *reinterpret_cast<const float4*>(in + i);
  ushort4 o;
  o.x = f2bf(f.x); o.y = f2bf(f.y); o.z = f2bf(f.z); o.w = f2bf(f.w);
  *reinterpret_cast<ushort4*>(out + i) = o;
}

#define GLOAD16(gsrc, ldst)                                                       \
  __builtin_amdgcn_global_load_lds(                                               \
      (const __attribute__((address_space(1))) void*)(gsrc),                      \
      (__attribute__((address_space(3))) void*)(ldst), 16, 0, 0)

#define WAITV_(n) asm volatile("s_waitcnt vmcnt(" #n ")" ::: "memory")
#define WAITV(n) WAITV_(n)
#define LDSB(off) (*reinterpret_cast<const bf16x8*>(&lds[(off)]))
#define MM(a, b, c) c = __builtin_amdgcn_mfma_f32_16x16x32_bf16(a, b, c, 0, 0, 0)

// stage one 8KB round: 64 rows (RB..RB+63) x 64 cols of the source panel,
// global source pre-swizzled so linear LDS holds slot ^= (row&7) layout.
#define STAGE_T(P, g0, kt, RB, reg)                                               \
  GLOAD16(P + (size_t)((g0) + (RB) + (tid >> 3)) * D_K + (kt) * 64 + swz8,        \
          lds + (reg) + (RB) * 128 + wv * 1024)

// A-frag pair for mi=2p,2p+1 + 16 MFMA (phase p), setprio-wrapped (T5)
#define MIPAIR(p, bAx)                                                            \
  {                                                                               \
    bf16x8 a00 = LDSB((bAx) + aoff0 + (p) * 4096 + sw0);                          \
    bf16x8 a01 = LDSB((bAx) + aoff0 + (p) * 4096 + sw1);                          \
    bf16x8 a10 = LDSB((bAx) + aoff0 + (p) * 4096 + 2048 + sw0);                   \
    bf16x8 a11 = LDSB((bAx) + aoff0 + (p) * 4096 + 2048 + sw1);                   \
    __builtin_amdgcn_s_setprio(1);                                                \
    MM(a00, b00, acc[2 * (p)][0]); MM(a01, b01, acc[2 * (p)][0]);                 \
    MM(a00, b10, acc[2 * (p)][1]); MM(a01, b11, acc[2 * (p)][1]);                 \
    MM(a00, b20, acc[2 * (p)][2]); MM(a01, b21, acc[2 * (p)][2]);                 \
    MM(a00, b30, acc[2 * (p)][3]); MM(a01, b31, acc[2 * (p)][3]);                 \
    MM(a10, b00, acc[2 * (p) + 1][0]); MM(a11, b01, acc[2 * (p) + 1][0]);         \
    MM(a10, b10, acc[2 * (p) + 1][1]); MM(a11, b11, acc[2 * (p) + 1][1]);         \
    MM(a10, b20, acc[2 * (p) + 1][2]); MM(a11, b21, acc[2 * (p) + 1][2]);         \
    MM(a10, b30, acc[2 * (p) + 1][3]); MM(a11, b31, acc[2 * (p) + 1][3]);         \
    __builtin_amdgcn_s_setprio(0);                                                \
  }

// One K-tile (BK=64), 4 phases. STG: stage tile t+1 into opposite buffer.
// vmcnt counts derived in journal: steady {ph0:4, ph2:6}, tail {2, 0}.
#define TILE(t, STG, VM0x, VM2x)                                                  \
  {                                                                               \
    const int bA = ((t) & 1) << 16; const int bB = bA + 32768;                    \
    const int oA = bA ^ 65536;      const int oB = oA + 32768;                    \
    /* phase 0: mi 0,1 */                                                         \
    if (STG) { STAGE_T(Sbf, cb0, (t) + 1, 0, oB); STAGE_T(Sbf, cb0, (t) + 1, 64, oB); } \
    WAITV(VM0x);                                                                  \
    __builtin_amdgcn_s_barrier();                                                 \
    bf16x8 b00 = LDSB(bB + boff0 + 0 * 2048 + sw0), b01 = LDSB(bB + boff0 + 0 * 2048 + sw1); \
    bf16x8 b10 = LDSB(bB + boff0 + 1 * 2048 + sw0), b11 = LDSB(bB + boff0 + 1 * 2048 + sw1); \
    bf16x8 b20 = LDSB(bB + boff0 + 2 * 2048 + sw0), b21 = LDSB(bB + boff0 + 2 * 2048 + sw1); \
    bf16x8 b30 = LDSB(bB + boff0 + 3 * 2048 + sw0), b31 = LDSB(bB + boff0 + 3 * 2048 + sw1); \
    MIPAIR(0, bA);                                                                \
    /* phase 1: mi 2,3 */                                                         \
    if (STG) { STAGE_T(Sbf, cb0, (t) + 1, 128, oB); STAGE_T(Sbf, cb0, (t) + 1, 192, oB); } \
    MIPAIR(1, bA);                                                                \
    /* phase 2: mi 4,5 */                                                         \
    if (STG) { STAGE_T(Ibf, rb0, (t) + 1, 0, oA); STAGE_T(Ibf, rb0, (t) + 1, 128, oA); } \
    WAITV(VM2x);                                                                  \
    __builtin_amdgcn_s_barrier();                                                 \
    MIPAIR(2, bA);                                                                \
    /* phase 3: mi 6,7 */                                                         \
    if (STG) { STAGE_T(Ibf, rb0, (t) + 1, 64, oA); STAGE_T(Ibf, rb0, (t) + 1, 192, oA); } \
    MIPAIR(3, bA);                                                                \
  }

// 256x256 tile, BK=64, 8 waves (2M x 4N), 512 threads, 128 KiB LDS dbuf.
// PHASE 1: row max/argmax (excl diag) + col raw max + diag
// PHASE 2: row/col exp-sums of hard_logits
template <int PHASE>
__launch_bounds__(512, 2)
__global__ void gemm_phase(const unsigned short* __restrict__ Ibf,
                           const unsigned short* __restrict__ Sbf,
                           unsigned long long* __restrict__ rowPack,
                           unsigned* __restrict__ colKey,
                           float* __restrict__ diag,
                           const float* __restrict__ Mrow,
                           const int* __restrict__ hardest,
                           float* __restrict__ rowsum,
                           float* __restrict__ colsum) {
  __shared__ char lds[131072];  // [buf][A 32K | B 32K]

  const int tid = threadIdx.x;
  const int lane = tid & 63;
  const int wv = tid >> 6;      // 0..7
  const int wr = wv >> 2;       // 0..1 (M)
  const int wc = wv & 3;        // 0..3 (N)
  const int l15 = lane & 15;
  const int g4 = lane >> 4;

  // T1: XCD-bijective block swizzle (1024 blocks, 1024%8==0)
  int bid = blockIdx.y * 32 + blockIdx.x;
  bid = (bid & 7) * 128 + (bid >> 3);
  const int rb0 = (bid >> 5) * 256;
  const int cb0 = (bid & 31) * 256;

  // staging source swizzle (elements): logical slot = (tid&7)^((tid>>3)&7)
  const int swz8 = (((tid & 7) ^ ((tid >> 3) & 7))) * 8;

  // ds_read bases / swizzled 16B-slot offsets (row&7 == l15&7)
  const int aoff0 = (wr * 128 + l15) * 128;
  const int boff0 = (wc * 64 + l15) * 128;
  const int sw0 = ((g4) ^ (l15 & 7)) * 16;        // ksub=0
  const int sw1 = ((4 + g4) ^ (l15 & 7)) * 16;    // ksub=1

  f32x4 acc[8][4] = {};

  // prologue: stage tile 0 into buf0 (stream order B0,B1,B2,B3,R0,R1,R2,R3)
  STAGE_T(Sbf, cb0, 0, 0, 32768);  STAGE_T(Sbf, cb0, 0, 64, 32768);
  STAGE_T(Sbf, cb0, 0, 128, 32768); STAGE_T(Sbf, cb0, 0, 192, 32768);
  STAGE_T(Ibf, rb0, 0, 0, 0);      STAGE_T(Ibf, rb0, 0, 128, 0);
  STAGE_T(Ibf, rb0, 0, 64, 0);     STAGE_T(Ibf, rb0, 0, 192, 0);

  TILE(0, 1, 4, 6)
  TILE(1, 1, 4, 6)
  TILE(2, 1, 4, 6)
  TILE(3, 1, 4, 6)
  TILE(4, 1, 4, 6)
  TILE(5, 1, 4, 6)
  TILE(6, 1, 4, 6)
  TILE(7, 0, 2, 0)

  // ---- epilogue (per-wave independent; grow/gcol per verified C/D layout) ----
  if (PHASE == 1) {
#pragma unroll
    for (int mi = 0; mi < 8; ++mi) {
#pragma unroll
      for (int v = 0; v < 4; ++v) {
        int grow = rb0 + wr * 128 + mi * 16 + g4 * 4 + v;
        float best = -3.4e38f;
        int bcol = 0;
#pragma unroll
        for (int ni = 0; ni < 4; ++ni) {
          float val = acc[mi][ni][v] * TEMP_INV;
          int gcol = cb0 + wc * 64 + ni * 16 + l15;
          if (gcol == grow) {
            diag[grow] = val;
          } else if (val > best) {
            best = val;
            bcol = gcol;
          }
        }
        for (int off = 1; off < 16; off <<= 1) {
          float ov = __shfl_xor(best, off);
          int oc = __shfl_xor(bcol, off);
          if (ov > best || (ov == best && oc < bcol)) { best = ov; bcol = oc; }
        }
        if (l15 == 0) {
          unsigned long long pk =
              ((unsigned long long)fkey(best) << 32) | (unsigned)(8191 - bcol);
          atomicMax(&rowPack[grow], pk);
        }
      }
    }
#pragma unroll
    for (int ni = 0; ni < 4; ++ni) {
      float best = -3.4e38f;
#pragma unroll
      for (int mi = 0; mi < 8; ++mi)
#pragma unroll
        for (int v = 0; v < 4; ++v)
          best = fmaxf(best, acc[mi][ni][v] * TEMP_INV);
      best = fmaxf(best, __shfl_xor(best, 16));
      best = fmaxf(best, __shfl_xor(best, 32));
      if (g4 == 0) atomicMax(&colKey[cb0 + wc * 64 + ni * 16 + l15], fkey(best));
    }
  } else {
    float cs[4] = {0.f, 0.f, 0.f, 0.f};
    float Nc[4];
#pragma unroll
    for (int ni = 0; ni < 4; ++ni) Nc[ni] = unkey(colKey[cb0 + wc * 64 + ni * 16 + l15]);
#pragma unroll
    for (int mi = 0; mi < 8; ++mi) {
#pragma unroll
      for (int v = 0; v < 4; ++v) {
        int grow = rb0 + wr * 128 + mi * 16 + g4 * 4 + v;
        float M = Mrow[grow];
        int hd = hardest[grow];
        float rs = 0.f;
#pragma unroll
        for (int ni = 0; ni < 4; ++ni) {
          int gcol = cb0 + wc * 64 + ni * 16 + l15;
          float val = acc[mi][ni][v] * TEMP_INV;
          float hl = (gcol == hd) ? HNW * val : val;
          rs += __expf(hl - M);
          cs[ni] += __expf(hl - Nc[ni]);
        }
        for (int off = 1; off < 16; off <<= 1) rs += __shfl_xor(rs, off);
        if (l15 == 0) atomicAdd(&rowsum[grow], rs);
      }
    }
#pragma unroll
    for (int ni = 0; ni < 4; ++ni) {
      cs[ni] += __shfl_xor(cs[ni], 16);
      cs[ni] += __shfl_xor(cs[ni], 32);
      if (g4 == 0) atomicAdd(&colsum[cb0 + wc * 64 + ni * 16 + l15], cs[ni]);
    }
  }
}

__global__ void mid_kernel(const unsigned long long* __restrict__ rowPack,
                           const float* __restrict__ diag,
                           float* __restrict__ Mrow,
                           int* __restrict__ hardest,
                           unsigned* __restrict__ colKey) {
  int i = blockIdx.x * 256 + threadIdx.x;
  unsigned long long pk = rowPack[i];
  float h = unkey((unsigned)(pk >> 32));
  int idx = 8191 - (int)(pk & 0xFFFFFFFFu);
  hardest[i] = idx;
  float hs = HNW * h;
  Mrow[i] = fmaxf(fmaxf(h, hs), diag[i]);
  atomicMax(&colKey[idx], fkey(hs));  // column max of hard_logits
}

__global__ void finalize_kernel(const float* __restrict__ Mrow,
                                const float* __restrict__ rowsum,
                                const unsigned* __restrict__ colKey,
                                const float* __restrict__ colsum,
                                const float* __restrict__ diag,
                                float* __restrict__ out) {
  __shared__ double red[256];
  double acc = 0.0;
  for (int i = threadIdx.x; i < B_N; i += 256) {
    float rowLSE = Mrow[i] + logf(rowsum[i]);
    float colLSE = unkey(colKey[i]) + logf(colsum[i]);
    acc += 0.5 * ((double)rowLSE + (double)colLSE) - (double)diag[i];
  }
  red[threadIdx.x] = acc;
  __syncthreads();
  for (int s = 128; s > 0; s >>= 1) {
    if (threadIdx.x < s) red[threadIdx.x] += red[threadIdx.x + s];
    __syncthreads();
  }
  if (threadIdx.x == 0) out[0] = (float)(red[0] / (double)B_N);
}

extern "C" void kernel_launch(void* const* d_in, const int* in_sizes, int n_in,
                              void* d_out, int out_size, void* d_ws, size_t ws_size,
                              hipStream_t stream) {
  const float* img = (const float*)d_in[0];
  const float* sng = (const float*)d_in[1];
  char* ws = (char*)d_ws;

  // workspace layout (bytes)
  unsigned short* Ibf = (unsigned short*)(ws);                       // 8 MB
  unsigned short* Sbf = (unsigned short*)(ws + 8388608);             // 8 MB
  unsigned long long* rowPack = (unsigned long long*)(ws + 16777216);// 64 KB (zeroed)
  unsigned* colKey = (unsigned*)(ws + 16842752);                     // 32 KB (zeroed)
  float* rowsum = (float*)(ws + 16875520);                           // 32 KB (zeroed)
  float* colsum = (float*)(ws + 16908288);                           // 32 KB (zeroed)
  float* diag = (float*)(ws + 16941056);                             // 32 KB
  float* Mrow = (float*)(ws + 16973824);                             // 32 KB
  int* hardest = (int*)(ws + 17006592);                              // 32 KB
  if (ws_size < 17039360) return;

  hipMemsetAsync(ws + 16777216, 0, 163840, stream);
  cvt_kernel<<<4096, 256, 0, stream>>>(img, Ibf);
  cvt_kernel<<<4096, 256, 0, stream>>>(sng, Sbf);
  dim3 g(32, 32);
  gemm_phase<1><<<g, 512, 0, stream>>>(Ibf, Sbf, rowPack, colKey, diag, Mrow, hardest, rowsum, colsum);
  mid_kernel<<<32, 256, 0, stream>>>(rowPack, diag, Mrow, hardest, colKey);
  gemm_phase<2><<<g, 512, 0, stream>>>(Ibf, Sbf, rowPack, colKey, diag, Mrow, hardest, rowsum, colsum);
  finalize_kernel<<<1, 256, 0, stream>>>(Mrow, rowsum, colKey, colsum, diag, (float*)d_out);
}